// Round 3
// baseline (5084.984 us; speedup 1.0000x reference)
//
#include <hip/hip_runtime.h>
#include <hip/hip_bf16.h>

// Problem constants
#define B_   2
#define S_   2048
#define DIM_ 4096
#define H_   32
#define KV_  8
#define HD_  128
#define MROWS_ (B_ * S_)   // 4096

typedef __attribute__((ext_vector_type(8))) short short8;
typedef __attribute__((ext_vector_type(4))) float floatx4;

__device__ __forceinline__ float bf2f(unsigned short u) {
    union { unsigned int i; float f; } v; v.i = ((unsigned int)u) << 16; return v.f;
}

// fp32 -> bf16 bits, round-to-nearest-even (inputs are finite; no NaN path)
__device__ __forceinline__ unsigned int f2bf(float f) {
    union { float f; unsigned int u; } v; v.f = f;
    unsigned int lsb = (v.u >> 16) & 1u;
    v.u += 0x7fffu + lsb;
    return v.u >> 16;
}
__device__ __forceinline__ unsigned int pack2bf(float lo, float hi) {
    return f2bf(lo) | (f2bf(hi) << 16);
}

// Load 8 contiguous elements as bf16 bits packed in a uint4 (no unaligned UB).
__device__ __forceinline__ uint4 load8cvt(const float* __restrict__ src) {
    const float4 a = ((const float4*)src)[0];
    const float4 b = ((const float4*)src)[1];
    uint4 r;
    r.x = pack2bf(a.x, a.y);
    r.y = pack2bf(a.z, a.w);
    r.z = pack2bf(b.x, b.y);
    r.w = pack2bf(b.z, b.w);
    return r;
}
__device__ __forceinline__ uint4 load8cvt(const __hip_bfloat16* __restrict__ src) {
    return *(const uint4*)src;
}

// Output store: fp32 direct, or bf16 convert.
__device__ __forceinline__ void storeC(float* p, float v) { *p = v; }
__device__ __forceinline__ void storeC(__hip_bfloat16* p, float v) { *p = __float2bfloat16(v); }

// ---------------------------------------------------------------------------
// GEMM: C[M,N] = A[M,K] @ B[K,N]; A/B fp32 or bf16 (converted to bf16 during
// LDS staging), fp32 accumulate via MFMA 16x16x32, TC output (fp32 or bf16).
// 256 threads, 128x128 C-tile, 4 waves 2x2, each wave 64x64 via 4x4 MFMAs.
// A-frag: lane holds A[m=lane&15][k=(lane>>4)*8+j]; B-frag mirrored;
// C/D: col=lane&15, row=(lane>>4)*4+reg (HW-verified layouts).
// ---------------------------------------------------------------------------
template <typename TA, typename TB, typename TC>
__global__ __launch_bounds__(256)
void gemm_any(const TA* __restrict__ A,
              const TB* __restrict__ B,
              TC* __restrict__ C,
              int M, int N, int K)
{
    __shared__ unsigned short As[128][40];   // 128x32 tile, +8 pad
    __shared__ unsigned short Bs[32][136];   // 32x128 tile, +8 pad

    const int tid  = threadIdx.x;
    const int lane = tid & 63;
    const int wid  = tid >> 6;
    const int wm = (wid >> 1) * 64;
    const int wn = (wid & 1) * 64;

    const int m0 = blockIdx.y * 128;
    const int n0 = blockIdx.x * 128;

    floatx4 acc[4][4];
    {
        floatx4 z = {0.f, 0.f, 0.f, 0.f};
        #pragma unroll
        for (int i = 0; i < 4; ++i)
            #pragma unroll
            for (int j = 0; j < 4; ++j)
                acc[i][j] = z;
    }

    const int a_row = tid >> 2;          // 0..63
    const int a_kc  = (tid & 3) * 8;     // 0,8,16,24
    const int b_kr  = tid >> 4;          // 0..15
    const int b_nc  = (tid & 15) * 8;    // 0..120

    const int fm = lane & 15;
    const int fk = (lane >> 4) * 8;

    for (int k0 = 0; k0 < K; k0 += 32) {
        uint4 av0 = load8cvt(A + (size_t)(m0 + a_row)      * K + k0 + a_kc);
        uint4 av1 = load8cvt(A + (size_t)(m0 + a_row + 64) * K + k0 + a_kc);
        uint4 bv0 = load8cvt(B + (size_t)(k0 + b_kr)       * N + n0 + b_nc);
        uint4 bv1 = load8cvt(B + (size_t)(k0 + b_kr + 16)  * N + n0 + b_nc);
        __syncthreads();   // previous iteration's LDS reads complete
        *(uint4*)&As[a_row][a_kc]      = av0;
        *(uint4*)&As[a_row + 64][a_kc] = av1;
        *(uint4*)&Bs[b_kr][b_nc]       = bv0;
        *(uint4*)&Bs[b_kr + 16][b_nc]  = bv1;
        __syncthreads();

        short8 afr[4], bfr[4];
        #pragma unroll
        for (int mi = 0; mi < 4; ++mi)
            afr[mi] = *(const short8*)&As[wm + mi * 16 + fm][fk];
        #pragma unroll
        for (int ni = 0; ni < 4; ++ni) {
            const int n = wn + ni * 16 + fm;
            short8 bb;
            #pragma unroll
            for (int j = 0; j < 8; ++j)
                bb[j] = (short)Bs[fk + j][n];
            bfr[ni] = bb;
        }
        #pragma unroll
        for (int mi = 0; mi < 4; ++mi)
            #pragma unroll
            for (int ni = 0; ni < 4; ++ni)
                acc[mi][ni] = __builtin_amdgcn_mfma_f32_16x16x32_bf16(
                    afr[mi], bfr[ni], acc[mi][ni], 0, 0, 0);
    }

    const int cl = lane & 15;
    const int rq = (lane >> 4) * 4;
    #pragma unroll
    for (int mi = 0; mi < 4; ++mi) {
        #pragma unroll
        for (int ni = 0; ni < 4; ++ni) {
            const int col = n0 + wn + ni * 16 + cl;
            #pragma unroll
            for (int r = 0; r < 4; ++r) {
                const int row = m0 + wm + mi * 16 + rq + r;
                storeC(C + (size_t)row * N + col, acc[mi][ni][r]);
            }
        }
    }
}

// ---------------------------------------------------------------------------
// RoPE in-place on T (bf16): [B*S, NH, 128]. cos/sin are fp32 [S,1,128].
// out[d]    = t[d]*cos[d]       - t[d+64]*sin[d]
// out[d+64] = t[d+64]*cos[d+64] + t[d]*sin[d+64]
// ---------------------------------------------------------------------------
__global__ void rope_kernel(__hip_bfloat16* __restrict__ T,
                            const float* __restrict__ cosb,
                            const float* __restrict__ sinb,
                            int NH, int total)
{
    int idx = blockIdx.x * blockDim.x + threadIdx.x;
    if (idx >= total) return;
    const int dh   = idx & 63;
    const int rest = idx >> 6;
    const int h    = rest % NH;
    const int bs   = rest / NH;       // b*S + s
    const int s    = bs & (S_ - 1);
    const size_t base = ((size_t)bs * NH + h) * HD_;
    const float t1 = __bfloat162float(T[base + dh]);
    const float t2 = __bfloat162float(T[base + dh + 64]);
    const float c1 = cosb[s * HD_ + dh];
    const float s1 = sinb[s * HD_ + dh];
    const float c2 = cosb[s * HD_ + dh + 64];
    const float s2 = sinb[s * HD_ + dh + 64];
    T[base + dh]      = __float2bfloat16(t1 * c1 - t2 * s1);
    T[base + dh + 64] = __float2bfloat16(t2 * c2 + t1 * s2);
}

// ---------------------------------------------------------------------------
// Flash attention (VALU fp32, online softmax). Block = (b,h) x 32-row q-tile.
// K/V tiles of 64 rows share one LDS buffer (K consumed before V load).
// Thread owns (q-row = tid>>3, dims (tid&7)*16..+16) for the O accumulator.
// ---------------------------------------------------------------------------
__global__ __launch_bounds__(256)
void attn_flash(const __hip_bfloat16* __restrict__ Q,
                const __hip_bfloat16* __restrict__ K,
                const __hip_bfloat16* __restrict__ V,
                __hip_bfloat16* __restrict__ O)
{
    const int qt = blockIdx.x;          // 0..63
    const int bh = blockIdx.y;          // 0..63
    const int b  = bh >> 5;
    const int h  = bh & 31;
    const int g  = h >> 2;              // kv head = h / REP
    const int q0 = qt * 32;

    __shared__ float Qs[32][128];             // scaled fp32 Q tile
    __shared__ unsigned short KVs[64][136];   // K then V tile (bf16 bits)
    __shared__ float St[32][64];              // scores -> probs
    __shared__ float mrow[32], lrow[32], arow[32];

    const int tid   = threadIdx.x;
    const int r_own = tid >> 3;
    const int d_own = (tid & 7) * 16;

    {   // load + scale Q tile
        const __hip_bfloat16* qp =
            Q + ((size_t)((b * S_ + q0 + r_own) * H_ + h)) * HD_ + d_own;
        #pragma unroll
        for (int i = 0; i < 16; ++i)
            Qs[r_own][d_own + i] = __bfloat162float(qp[i]) * 0.088388347648318447f;
    }
    if (tid < 32) { mrow[tid] = -1e30f; lrow[tid] = 0.f; }

    float out[16];
    #pragma unroll
    for (int i = 0; i < 16; ++i) out[i] = 0.f;

    const int kend = q0 + 31;
    for (int k0 = 0; k0 <= kend; k0 += 64) {
        __syncthreads();   // prev iter's KVs/St reads done; Qs ready on iter 0
        {   // K tile -> LDS
            const int kr = tid >> 2;
            const int d  = (tid & 3) * 32;
            const uint4* kp = (const uint4*)(
                K + ((size_t)((b * S_ + k0 + kr) * KV_ + g)) * HD_ + d);
            uint4 t0 = kp[0], t1 = kp[1], t2 = kp[2], t3 = kp[3];
            *(uint4*)&KVs[kr][d]      = t0;
            *(uint4*)&KVs[kr][d + 8]  = t1;
            *(uint4*)&KVs[kr][d + 16] = t2;
            *(uint4*)&KVs[kr][d + 24] = t3;
        }
        __syncthreads();
        {   // scores: thread -> (row r, keys kb..kb+7)
            const int r  = tid >> 3;
            const int kb = (tid & 7) * 8;
            float sc[8];
            #pragma unroll
            for (int j = 0; j < 8; ++j) sc[j] = 0.f;
            for (int dc = 0; dc < 128; dc += 8) {
                float qv[8];
                #pragma unroll
                for (int i = 0; i < 8; ++i) qv[i] = Qs[r][dc + i];
                #pragma unroll
                for (int j = 0; j < 8; ++j) {
                    uint4 kv = *(const uint4*)&KVs[kb + j][dc];
                    const unsigned short* ks = (const unsigned short*)&kv;
                    float s = sc[j];
                    #pragma unroll
                    for (int i = 0; i < 8; ++i) s += qv[i] * bf2f(ks[i]);
                    sc[j] = s;
                }
            }
            const int qg = q0 + r;
            #pragma unroll
            for (int j = 0; j < 8; ++j)
                St[r][kb + j] = (k0 + kb + j <= qg) ? sc[j] : -1e30f;
        }
        __syncthreads();
        if (tid < 32) {   // online softmax per row
            const int r = tid;
            float mx = mrow[r];
            for (int j = 0; j < 64; ++j) mx = fmaxf(mx, St[r][j]);
            const float alpha = __expf(mrow[r] - mx);
            float sum = 0.f;
            for (int j = 0; j < 64; ++j) {
                const float p = __expf(St[r][j] - mx);
                St[r][j] = p;
                sum += p;
            }
            mrow[r] = mx;
            lrow[r] = lrow[r] * alpha + sum;
            arow[r] = alpha;
        }
        __syncthreads();
        {   // rescale O accumulator
            const float alpha = arow[r_own];
            #pragma unroll
            for (int i = 0; i < 16; ++i) out[i] *= alpha;
        }
        {   // V tile -> LDS (K fully consumed)
            const int kr = tid >> 2;
            const int d  = (tid & 3) * 32;
            const uint4* vp = (const uint4*)(
                V + ((size_t)((b * S_ + k0 + kr) * KV_ + g)) * HD_ + d);
            uint4 t0 = vp[0], t1 = vp[1], t2 = vp[2], t3 = vp[3];
            *(uint4*)&KVs[kr][d]      = t0;
            *(uint4*)&KVs[kr][d + 8]  = t1;
            *(uint4*)&KVs[kr][d + 16] = t2;
            *(uint4*)&KVs[kr][d + 24] = t3;
        }
        __syncthreads();
        {   // P @ V accumulate
            for (int j = 0; j < 64; ++j) {
                const float p = St[r_own][j];
                uint4 v0 = *(const uint4*)&KVs[j][d_own];
                uint4 v1 = *(const uint4*)&KVs[j][d_own + 8];
                const unsigned short* vs0 = (const unsigned short*)&v0;
                const unsigned short* vs1 = (const unsigned short*)&v1;
                #pragma unroll
                for (int i = 0; i < 8; ++i) out[i]     += p * bf2f(vs0[i]);
                #pragma unroll
                for (int i = 0; i < 8; ++i) out[i + 8] += p * bf2f(vs1[i]);
            }
        }
    }
    {   // finalize
        const float inv_l = 1.f / lrow[r_own];
        __hip_bfloat16* op =
            O + ((size_t)((b * S_ + q0 + r_own) * H_ + h)) * HD_ + d_own;
        #pragma unroll
        for (int i = 0; i < 16; ++i)
            op[i] = __float2bfloat16(out[i] * inv_l);
    }
}

// ---------------------------------------------------------------------------
extern "C" void kernel_launch(void* const* d_in, const int* in_sizes, int n_in,
                              void* d_out, int out_size, void* d_ws, size_t ws_size,
                              hipStream_t stream)
{
    // Inputs fp32 per the reference's setup_inputs; output fp32 per the
    // reference's return dtype (harness contract).
    const float* x    = (const float*)d_in[0];
    const float* cosb = (const float*)d_in[1];
    const float* sinb = (const float*)d_in[2];
    const float* Wq   = (const float*)d_in[3];
    const float* Wk   = (const float*)d_in[4];
    const float* Wv   = (const float*)d_in[5];
    const float* Wo   = (const float*)d_in[6];
    float* out = (float*)d_out;

    // Workspace layout (80 MB total):
    //   Q  [4096,4096] bf16 : 32 MB @ 0
    //   K  [4096,1024] bf16 :  8 MB @ 32 MB
    //   V  [4096,1024] bf16 :  8 MB @ 40 MB
    //   Ao [4096,4096] bf16 : 32 MB @ 48 MB
    char* ws = (char*)d_ws;
    __hip_bfloat16* Qb = (__hip_bfloat16*)(ws);
    __hip_bfloat16* Kb = (__hip_bfloat16*)(ws + (size_t)32 * 1024 * 1024);
    __hip_bfloat16* Vb = (__hip_bfloat16*)(ws + (size_t)40 * 1024 * 1024);
    __hip_bfloat16* Ab = (__hip_bfloat16*)(ws + (size_t)48 * 1024 * 1024);

    dim3 blk(256);

    // Projections (fp32 inputs, bf16 MFMA compute, bf16 out to ws)
    gemm_any<float, float, __hip_bfloat16>
        <<<dim3(DIM_ / 128, MROWS_ / 128), blk, 0, stream>>>(
        x, Wq, Qb, MROWS_, DIM_, DIM_);
    gemm_any<float, float, __hip_bfloat16>
        <<<dim3((KV_ * HD_) / 128, MROWS_ / 128), blk, 0, stream>>>(
        x, Wk, Kb, MROWS_, KV_ * HD_, DIM_);
    gemm_any<float, float, __hip_bfloat16>
        <<<dim3((KV_ * HD_) / 128, MROWS_ / 128), blk, 0, stream>>>(
        x, Wv, Vb, MROWS_, KV_ * HD_, DIM_);

    // RoPE (in-place, bf16 tensors, fp32 tables)
    {
        int totq = MROWS_ * H_ * 64;
        int totk = MROWS_ * KV_ * 64;
        rope_kernel<<<(totq + 255) / 256, blk, 0, stream>>>(Qb, cosb, sinb, H_, totq);
        rope_kernel<<<(totk + 255) / 256, blk, 0, stream>>>(Kb, cosb, sinb, KV_, totk);
    }

    // Attention
    attn_flash<<<dim3(S_ / 32, B_ * H_), blk, 0, stream>>>(Qb, Kb, Vb, Ab);

    // Output projection: bf16 attention output x fp32 Wo -> fp32 out
    gemm_any<__hip_bfloat16, float, float>
        <<<dim3(DIM_ / 128, MROWS_ / 128), blk, 0, stream>>>(
        Ab, Wo, out, MROWS_, DIM_, DIM_);
}

// Round 4
// 1776.018 us; speedup vs baseline: 2.8631x; 2.8631x over previous
//
#include <hip/hip_runtime.h>
#include <hip/hip_bf16.h>

// Problem constants
#define B_   2
#define S_   2048
#define DIM_ 4096
#define H_   32
#define KV_  8
#define HD_  128
#define MROWS_ (B_ * S_)   // 4096

typedef __attribute__((ext_vector_type(8))) short short8;
typedef __attribute__((ext_vector_type(4))) float floatx4;

__device__ __forceinline__ float bf2f(unsigned short u) {
    union { unsigned int i; float f; } v; v.i = ((unsigned int)u) << 16; return v.f;
}

// fp32 -> bf16 bits, round-to-nearest-even (inputs are finite; no NaN path)
__device__ __forceinline__ unsigned int f2bf(float f) {
    union { float f; unsigned int u; } v; v.f = f;
    unsigned int lsb = (v.u >> 16) & 1u;
    v.u += 0x7fffu + lsb;
    return v.u >> 16;
}
__device__ __forceinline__ unsigned int pack2bf(float lo, float hi) {
    return f2bf(lo) | (f2bf(hi) << 16);
}

// Load 8 contiguous elements as bf16 bits packed in a uint4.
__device__ __forceinline__ uint4 load8cvt(const float* __restrict__ src) {
    const float4 a = ((const float4*)src)[0];
    const float4 b = ((const float4*)src)[1];
    uint4 r;
    r.x = pack2bf(a.x, a.y);
    r.y = pack2bf(a.z, a.w);
    r.z = pack2bf(b.x, b.y);
    r.w = pack2bf(b.z, b.w);
    return r;
}
__device__ __forceinline__ uint4 load8cvt(const __hip_bfloat16* __restrict__ src) {
    return *(const uint4*)src;
}

__device__ __forceinline__ void storeC(float* p, float v) { *p = v; }
__device__ __forceinline__ void storeC(__hip_bfloat16* p, float v) { *p = __float2bfloat16(v); }

// ---------------------------------------------------------------------------
// GEMM: C[M,N] = A[M,K] @ B[K,N]; A/B fp32 or bf16 (converted to bf16 during
// LDS staging), fp32 accumulate via MFMA 16x16x32, TC output (fp32 or bf16).
// ---------------------------------------------------------------------------
template <typename TA, typename TB, typename TC>
__global__ __launch_bounds__(256)
void gemm_any(const TA* __restrict__ A,
              const TB* __restrict__ B,
              TC* __restrict__ C,
              int M, int N, int K)
{
    __shared__ unsigned short As[128][40];   // 128x32 tile, +8 pad
    __shared__ unsigned short Bs[32][136];   // 32x128 tile, +8 pad

    const int tid  = threadIdx.x;
    const int lane = tid & 63;
    const int wid  = tid >> 6;
    const int wm = (wid >> 1) * 64;
    const int wn = (wid & 1) * 64;

    const int m0 = blockIdx.y * 128;
    const int n0 = blockIdx.x * 128;

    floatx4 acc[4][4];
    {
        floatx4 z = {0.f, 0.f, 0.f, 0.f};
        #pragma unroll
        for (int i = 0; i < 4; ++i)
            #pragma unroll
            for (int j = 0; j < 4; ++j)
                acc[i][j] = z;
    }

    const int a_row = tid >> 2;          // 0..63
    const int a_kc  = (tid & 3) * 8;     // 0,8,16,24
    const int b_kr  = tid >> 4;          // 0..15
    const int b_nc  = (tid & 15) * 8;    // 0..120

    const int fm = lane & 15;
    const int fk = (lane >> 4) * 8;

    for (int k0 = 0; k0 < K; k0 += 32) {
        uint4 av0 = load8cvt(A + (size_t)(m0 + a_row)      * K + k0 + a_kc);
        uint4 av1 = load8cvt(A + (size_t)(m0 + a_row + 64) * K + k0 + a_kc);
        uint4 bv0 = load8cvt(B + (size_t)(k0 + b_kr)       * N + n0 + b_nc);
        uint4 bv1 = load8cvt(B + (size_t)(k0 + b_kr + 16)  * N + n0 + b_nc);
        __syncthreads();   // previous iteration's LDS reads complete
        *(uint4*)&As[a_row][a_kc]      = av0;
        *(uint4*)&As[a_row + 64][a_kc] = av1;
        *(uint4*)&Bs[b_kr][b_nc]       = bv0;
        *(uint4*)&Bs[b_kr + 16][b_nc]  = bv1;
        __syncthreads();

        short8 afr[4], bfr[4];
        #pragma unroll
        for (int mi = 0; mi < 4; ++mi)
            afr[mi] = *(const short8*)&As[wm + mi * 16 + fm][fk];
        #pragma unroll
        for (int ni = 0; ni < 4; ++ni) {
            const int n = wn + ni * 16 + fm;
            short8 bb;
            #pragma unroll
            for (int j = 0; j < 8; ++j)
                bb[j] = (short)Bs[fk + j][n];
            bfr[ni] = bb;
        }
        #pragma unroll
        for (int mi = 0; mi < 4; ++mi)
            #pragma unroll
            for (int ni = 0; ni < 4; ++ni)
                acc[mi][ni] = __builtin_amdgcn_mfma_f32_16x16x32_bf16(
                    afr[mi], bfr[ni], acc[mi][ni], 0, 0, 0);
    }

    const int cl = lane & 15;
    const int rq = (lane >> 4) * 4;
    #pragma unroll
    for (int mi = 0; mi < 4; ++mi) {
        #pragma unroll
        for (int ni = 0; ni < 4; ++ni) {
            const int col = n0 + wn + ni * 16 + cl;
            #pragma unroll
            for (int r = 0; r < 4; ++r) {
                const int row = m0 + wm + mi * 16 + rq + r;
                storeC(C + (size_t)row * N + col, acc[mi][ni][r]);
            }
        }
    }
}

// ---------------------------------------------------------------------------
// RoPE in-place on T (bf16): [B*S, NH, 128]. cos/sin are fp32 [S,1,128].
// ---------------------------------------------------------------------------
__global__ void rope_kernel(__hip_bfloat16* __restrict__ T,
                            const float* __restrict__ cosb,
                            const float* __restrict__ sinb,
                            int NH, int total)
{
    int idx = blockIdx.x * blockDim.x + threadIdx.x;
    if (idx >= total) return;
    const int dh   = idx & 63;
    const int rest = idx >> 6;
    const int h    = rest % NH;
    const int bs   = rest / NH;       // b*S + s
    const int s    = bs & (S_ - 1);
    const size_t base = ((size_t)bs * NH + h) * HD_;
    const float t1 = __bfloat162float(T[base + dh]);
    const float t2 = __bfloat162float(T[base + dh + 64]);
    const float c1 = cosb[s * HD_ + dh];
    const float s1 = sinb[s * HD_ + dh];
    const float c2 = cosb[s * HD_ + dh + 64];
    const float s2 = sinb[s * HD_ + dh + 64];
    T[base + dh]      = __float2bfloat16(t1 * c1 - t2 * s1);
    T[base + dh + 64] = __float2bfloat16(t2 * c2 + t1 * s2);
}

// ---------------------------------------------------------------------------
// MFMA flash attention. Block = (b,h) x 128-row Q tile; 4 waves x 32 q-rows.
// Per 64-key iteration:
//   QK^T: A = Q-frags (registers, loaded once), B = Ks[key][d] (contiguous d)
//   softmax: C-layout scores; row stats via __shfl_xor over the 16-lane quad
//   P: exp'd probs -> bf16 -> per-wave LDS -> re-read as A-frags
//   PV:  B = Vt[d][key] (V transposed during staging; contiguous key)
// Layouts (HW-verified): A[m=lane&15][k=quad*8+j]; B[k=quad*8+j][n=lane&15];
// C/D[row=quad*4+r][col=lane&15].
// ---------------------------------------------------------------------------
#define LOG2E 1.4426950408889634f

__global__ __launch_bounds__(256)
void attn_mfma(const __hip_bfloat16* __restrict__ Q,
               const __hip_bfloat16* __restrict__ K,
               const __hip_bfloat16* __restrict__ V,
               __hip_bfloat16* __restrict__ O)
{
    const int qt = blockIdx.x;          // 0..15
    const int bh = blockIdx.y;          // 0..63
    const int b  = bh >> 5;
    const int h  = bh & 31;
    const int g  = h >> 2;              // kv head
    const int q0 = qt * 128;

    __shared__ unsigned short Ks[64][136];    // K tile, key-major (+8 pad)
    __shared__ unsigned short Vt[128][72];    // V tile transposed: [d][key]
    __shared__ unsigned short Ps[4][32][72];  // per-wave P (bf16)

    const int tid  = threadIdx.x;
    const int lane = tid & 63;
    const int w    = tid >> 6;
    const int fm   = lane & 15;
    const int quad = lane >> 4;
    const int fk   = quad * 8;

    const int qrow_base = q0 + w * 32;

    // Q A-fragments: [mt][dt], resident for whole kernel
    short8 qf[2][4];
    #pragma unroll
    for (int mt = 0; mt < 2; ++mt) {
        const int row = qrow_base + mt * 16 + fm;
        const __hip_bfloat16* qp = Q + ((size_t)(b * S_ + row) * H_ + h) * HD_;
        #pragma unroll
        for (int dt = 0; dt < 4; ++dt)
            qf[mt][dt] = *(const short8*)(qp + dt * 32 + fk);
    }

    floatx4 o_acc[2][8];
    {
        floatx4 z = {0.f, 0.f, 0.f, 0.f};
        #pragma unroll
        for (int mt = 0; mt < 2; ++mt)
            #pragma unroll
            for (int nt = 0; nt < 8; ++nt)
                o_acc[mt][nt] = z;
    }
    float m_r[2][4], l_r[2][4];
    #pragma unroll
    for (int mt = 0; mt < 2; ++mt)
        #pragma unroll
        for (int r = 0; r < 4; ++r) { m_r[mt][r] = -1e30f; l_r[mt][r] = 0.f; }

    const float scale = 0.08838834764831845f;   // 1/sqrt(128)

    const int ktiles = 2 * (qt + 1);
    for (int kt = 0; kt < ktiles; ++kt) {
        const int k0 = kt * 64;
        __syncthreads();   // prior iter's Ks/Vt reads complete
        {   // stage K (row-major) and V (transposed)
            const int key = tid >> 2;
            const int d0  = (tid & 3) * 32;
            const size_t goff = ((size_t)(b * S_ + k0 + key) * KV_ + g) * HD_ + d0;
            const uint4* kp = (const uint4*)((const unsigned short*)K + goff);
            const uint4* vp = (const uint4*)((const unsigned short*)V + goff);
            uint4 kv0 = kp[0], kv1 = kp[1], kv2 = kp[2], kv3 = kp[3];
            uint4 vv[4] = { vp[0], vp[1], vp[2], vp[3] };
            *(uint4*)&Ks[key][d0]      = kv0;
            *(uint4*)&Ks[key][d0 + 8]  = kv1;
            *(uint4*)&Ks[key][d0 + 16] = kv2;
            *(uint4*)&Ks[key][d0 + 24] = kv3;
            const unsigned short* vs = (const unsigned short*)vv;
            #pragma unroll
            for (int i = 0; i < 32; ++i)
                Vt[d0 + i][key] = vs[i];
        }
        __syncthreads();

        // ---- QK^T ----
        floatx4 s_acc[2][4];
        {
            floatx4 z = {0.f, 0.f, 0.f, 0.f};
            #pragma unroll
            for (int mt = 0; mt < 2; ++mt)
                #pragma unroll
                for (int nt = 0; nt < 4; ++nt)
                    s_acc[mt][nt] = z;
        }
        #pragma unroll
        for (int dt = 0; dt < 4; ++dt) {
            #pragma unroll
            for (int nt = 0; nt < 4; ++nt) {
                short8 bf = *(const short8*)&Ks[nt * 16 + fm][dt * 32 + fk];
                #pragma unroll
                for (int mt = 0; mt < 2; ++mt)
                    s_acc[mt][nt] = __builtin_amdgcn_mfma_f32_16x16x32_bf16(
                        qf[mt][dt], bf, s_acc[mt][nt], 0, 0, 0);
            }
        }

        // ---- mask + online softmax (per 16-lane quad) ----
        #pragma unroll
        for (int mt = 0; mt < 2; ++mt) {
            const int rowq0 = qrow_base + mt * 16 + quad * 4;
            #pragma unroll
            for (int r = 0; r < 4; ++r) {
                const int rowq = rowq0 + r;
                float mx = -1e30f;
                #pragma unroll
                for (int nt = 0; nt < 4; ++nt) {
                    const int c = k0 + nt * 16 + fm;
                    float s = s_acc[mt][nt][r] * scale;
                    s = (c <= rowq) ? s : -1e30f;
                    s_acc[mt][nt][r] = s;
                    mx = fmaxf(mx, s);
                }
                #pragma unroll
                for (int off = 1; off < 16; off <<= 1)
                    mx = fmaxf(mx, __shfl_xor(mx, off));
                const float mold = m_r[mt][r];
                const float mnew = fmaxf(mold, mx);
                const float alpha = __expf(mold - mnew);
                float rsum = 0.f;
                #pragma unroll
                for (int nt = 0; nt < 4; ++nt) {
                    const float p = __expf(s_acc[mt][nt][r] - mnew);
                    s_acc[mt][nt][r] = p;
                    rsum += p;
                }
                #pragma unroll
                for (int off = 1; off < 16; off <<= 1)
                    rsum += __shfl_xor(rsum, off);
                m_r[mt][r] = mnew;
                l_r[mt][r] = l_r[mt][r] * alpha + rsum;
                #pragma unroll
                for (int nt = 0; nt < 8; ++nt)
                    o_acc[mt][nt][r] *= alpha;
                // store P row to per-wave LDS (bf16)
                #pragma unroll
                for (int nt = 0; nt < 4; ++nt)
                    Ps[w][mt * 16 + quad * 4 + r][nt * 16 + fm] =
                        (unsigned short)f2bf(s_acc[mt][nt][r]);
            }
        }

        // ---- PV ----
        #pragma unroll
        for (int ct = 0; ct < 2; ++ct) {
            short8 af[2];
            #pragma unroll
            for (int mt = 0; mt < 2; ++mt)
                af[mt] = *(const short8*)&Ps[w][mt * 16 + fm][ct * 32 + fk];
            #pragma unroll
            for (int nt = 0; nt < 8; ++nt) {
                short8 bf = *(const short8*)&Vt[nt * 16 + fm][ct * 32 + fk];
                #pragma unroll
                for (int mt = 0; mt < 2; ++mt)
                    o_acc[mt][nt] = __builtin_amdgcn_mfma_f32_16x16x32_bf16(
                        af[mt], bf, o_acc[mt][nt], 0, 0, 0);
            }
        }
    }

    // ---- epilogue: normalize by l, store bf16 ----
    #pragma unroll
    for (int mt = 0; mt < 2; ++mt) {
        #pragma unroll
        for (int r = 0; r < 4; ++r) {
            const int row = qrow_base + mt * 16 + quad * 4 + r;
            const float inv_l = 1.f / l_r[mt][r];
            __hip_bfloat16* op = O + ((size_t)(b * S_ + row) * H_ + h) * HD_;
            #pragma unroll
            for (int nt = 0; nt < 8; ++nt)
                op[nt * 16 + fm] = __float2bfloat16(o_acc[mt][nt][r] * inv_l);
        }
    }
}

// ---------------------------------------------------------------------------
extern "C" void kernel_launch(void* const* d_in, const int* in_sizes, int n_in,
                              void* d_out, int out_size, void* d_ws, size_t ws_size,
                              hipStream_t stream)
{
    const float* x    = (const float*)d_in[0];
    const float* cosb = (const float*)d_in[1];
    const float* sinb = (const float*)d_in[2];
    const float* Wq   = (const float*)d_in[3];
    const float* Wk   = (const float*)d_in[4];
    const float* Wv   = (const float*)d_in[5];
    const float* Wo   = (const float*)d_in[6];
    float* out = (float*)d_out;

    // Workspace: Q 32MB | K 8MB | V 8MB | Ao 32MB  (all bf16)
    char* ws = (char*)d_ws;
    __hip_bfloat16* Qb = (__hip_bfloat16*)(ws);
    __hip_bfloat16* Kb = (__hip_bfloat16*)(ws + (size_t)32 * 1024 * 1024);
    __hip_bfloat16* Vb = (__hip_bfloat16*)(ws + (size_t)40 * 1024 * 1024);
    __hip_bfloat16* Ab = (__hip_bfloat16*)(ws + (size_t)48 * 1024 * 1024);

    dim3 blk(256);

    // Projections (fp32 inputs, bf16 MFMA compute, bf16 out to ws)
    gemm_any<float, float, __hip_bfloat16>
        <<<dim3(DIM_ / 128, MROWS_ / 128), blk, 0, stream>>>(
        x, Wq, Qb, MROWS_, DIM_, DIM_);
    gemm_any<float, float, __hip_bfloat16>
        <<<dim3((KV_ * HD_) / 128, MROWS_ / 128), blk, 0, stream>>>(
        x, Wk, Kb, MROWS_, KV_ * HD_, DIM_);
    gemm_any<float, float, __hip_bfloat16>
        <<<dim3((KV_ * HD_) / 128, MROWS_ / 128), blk, 0, stream>>>(
        x, Wv, Vb, MROWS_, KV_ * HD_, DIM_);

    // RoPE (in-place, bf16 tensors, fp32 tables)
    {
        int totq = MROWS_ * H_ * 64;
        int totk = MROWS_ * KV_ * 64;
        rope_kernel<<<(totq + 255) / 256, blk, 0, stream>>>(Qb, cosb, sinb, H_, totq);
        rope_kernel<<<(totk + 255) / 256, blk, 0, stream>>>(Kb, cosb, sinb, KV_, totk);
    }

    // MFMA flash attention
    attn_mfma<<<dim3(S_ / 128, B_ * H_), blk, 0, stream>>>(Qb, Kb, Vb, Ab);

    // Output projection: bf16 attention output x fp32 Wo -> fp32 out
    gemm_any<__hip_bfloat16, float, float>
        <<<dim3(DIM_ / 128, MROWS_ / 128), blk, 0, stream>>>(
        Ab, Wo, out, MROWS_, DIM_, DIM_);
}